// Round 9
// baseline (1373.618 us; speedup 1.0000x reference)
//
#include <hip/hip_runtime.h>
#include <hip/hip_bf16.h>
#include <math.h>

// Problem constants
#define NB 8
#define NSEQ 1024
#define M_ 1025                 // NSEQ + 1 (cls)
#define ROWS (NB * M_)          // 8200
#define DIMC 128
#define NHEADS 8
#define QKV3 3072               // 3*8*128
#define PEROWS (NB * NSEQ)      // 8192
#define ACS 1088                // vt padded column stride

typedef __attribute__((ext_vector_type(8))) short bf16x8;
typedef __attribute__((ext_vector_type(4))) float f32x4;

__device__ __forceinline__ float gelu_f(float x) {
  return 0.5f * x * (1.f + erff(x * 0.70710678118654752440f));
}

__device__ __forceinline__ unsigned short f2bf(float f) {
  __hip_bfloat16 h = __float2bfloat16(f);
  return *reinterpret_cast<unsigned short*>(&h);
}

__device__ __forceinline__ float bf2f(unsigned short u) {
  union { unsigned int i; float f; } c;
  c.i = ((unsigned int)u) << 16;
  return c.f;
}

// async global->LDS DMA, 16B per lane; LDS dest = wave-uniform base + lane*16
__device__ __forceinline__ void g2lds16(const void* g, void* l) {
  __builtin_amdgcn_global_load_lds(
      (__attribute__((address_space(1))) void*)(g),
      (__attribute__((address_space(3))) void*)(l), 16, 0, 0);
}

// ---------------------------------------------------------------------------
// PE matmul stage (R19: LDS weights, float4 k-groups, capped unroll)
// ---------------------------------------------------------------------------
template<int K, int KP, int C, int SS, int DOGELU>
__device__ __forceinline__ void pe_stage(
    int tid, const float* __restrict__ W, const float* __restrict__ B,
    const float* src, float* dst, float (*wb)[128])
{
  for (int i = tid; i < K * C; i += 128) wb[i / C][i % C] = W[i];
  if (tid < C) {
#pragma unroll
    for (int k = K; k < KP; ++k) wb[k][tid] = 0.f;
  }
  __syncthreads();
  if (tid < C) {
    float acc[16];
#pragma unroll
    for (int r = 0; r < 16; ++r) acc[r] = B[tid];
#pragma unroll 1
    for (int k4 = 0; k4 < KP; k4 += 4) {
      const float w0 = wb[k4 + 0][tid];
      const float w1 = wb[k4 + 1][tid];
      const float w2 = wb[k4 + 2][tid];
      const float w3 = wb[k4 + 3][tid];
#pragma unroll
      for (int r = 0; r < 16; ++r) {
        const float4 av = *(const float4*)&src[r * SS + k4];
        acc[r] = fmaf(av.x, w0, acc[r]);
        acc[r] = fmaf(av.y, w1, acc[r]);
        acc[r] = fmaf(av.z, w2, acc[r]);
        acc[r] = fmaf(av.w, w3, acc[r]);
      }
    }
#pragma unroll
    for (int r = 0; r < 16; ++r) dst[r * 72 + tid] = DOGELU ? gelu_f(acc[r]) : acc[r];
  }
  __syncthreads();
}

// ---------------------------------------------------------------------------
// Fused PE encoder
// ---------------------------------------------------------------------------
__global__ __launch_bounds__(128) void pe_fused_k(
    const float* __restrict__ nf, const float* __restrict__ lp,
    const float* __restrict__ w1, const float* __restrict__ b1,
    const float* __restrict__ w2, const float* __restrict__ b2,
    const float* __restrict__ w3, const float* __restrict__ b3,
    const float* __restrict__ lng, const float* __restrict__ lnb,
    const float* __restrict__ w4, const float* __restrict__ b4,
    float* __restrict__ x)
{
  __shared__ float sIn[16][36];
  __shared__ float sX[16][72];
  __shared__ float sY[16][72];
  __shared__ float wb[72][128];   // staged weights [k][c]
  const int tid = threadIdx.x;
  const int r0 = blockIdx.x * 16;

  for (int i = tid; i < 16 * 35; i += 128) {
    const int r = i / 35, c = i - r * 35;
    const int gr = r0 + r;
    sIn[r][c] = (c < 3) ? nf[(size_t)gr * 3 + c] : lp[(size_t)gr * 32 + (c - 3)];
  }
  if (tid < 16) {
    sIn[tid][35] = 0.f;
    sX[tid][70] = 0.f; sX[tid][71] = 0.f;   // pad cols stay zero forever
    sY[tid][70] = 0.f; sY[tid][71] = 0.f;
  }
  __syncthreads();

  pe_stage<35, 36, 70, 36, 1>(tid, w1, b1, &sIn[0][0], &sX[0][0], wb);
  pe_stage<70, 72, 70, 72, 1>(tid, w2, b2, &sX[0][0], &sY[0][0], wb);
  pe_stage<70, 72, 70, 72, 1>(tid, w3, b3, &sY[0][0], &sX[0][0], wb);

  if (tid < 16) {
    float m = 0.f;
    for (int d = 0; d < 70; ++d) m += sX[tid][d];
    m *= (1.f / 70.f);
    float v = 0.f;
    for (int d = 0; d < 70; ++d) { const float t = sX[tid][d] - m; v += t * t; }
    const float inv = rsqrtf(v * (1.f / 70.f) + 1e-5f);
    for (int d = 0; d < 70; ++d) sX[tid][d] = (sX[tid][d] - m) * inv * lng[d] + lnb[d];
  }
  __syncthreads();

  // final stage: C=128, direct global write with PE row mapping
  {
    for (int i = tid; i < 70 * 128; i += 128) wb[i >> 7][i & 127] = w4[i];
#pragma unroll
    for (int k = 70; k < 72; ++k) wb[k][tid] = 0.f;
    __syncthreads();
    float acc[16];
#pragma unroll
    for (int r = 0; r < 16; ++r) acc[r] = b4[tid];
#pragma unroll 1
    for (int k4 = 0; k4 < 72; k4 += 4) {
      const float w0 = wb[k4 + 0][tid];
      const float w1v = wb[k4 + 1][tid];
      const float w2v = wb[k4 + 2][tid];
      const float w3v = wb[k4 + 3][tid];
#pragma unroll
      for (int r = 0; r < 16; ++r) {
        const float4 av = *(const float4*)&sX[r][k4];
        acc[r] = fmaf(av.x, w0, acc[r]);
        acc[r] = fmaf(av.y, w1v, acc[r]);
        acc[r] = fmaf(av.z, w2v, acc[r]);
        acc[r] = fmaf(av.w, w3v, acc[r]);
      }
    }
#pragma unroll
    for (int r = 0; r < 16; ++r) {
      const int gr = r0 + r;
      x[(size_t)(gr + gr / 1024 + 1) * DIMC + tid] = acc[r];
    }
  }
}

// ---------------------------------------------------------------------------
// bf16 MFMA GEMM, 64x64 tile (mlp1 only now)
// ---------------------------------------------------------------------------
template<int ACT, int OBF, int RES>
__global__ __launch_bounds__(256) void mgemm_k(
    const unsigned short* __restrict__ Xb, const unsigned short* __restrict__ Wt,
    const float* __restrict__ bias, const float* __restrict__ res,
    void* __restrict__ outp, int rows, int K, int N)
{
  __shared__ unsigned short sX[64][72];
  __shared__ unsigned short sW[64][72];
  const int tid = threadIdx.x;
  const int w = tid >> 6, lane = tid & 63;
  const int col = lane & 15, quad = lane >> 4;
  const int r0 = blockIdx.x * 64, n0 = blockIdx.y * 64;
  const int lr = tid >> 2, lc = tid & 3;
  const int xrow = min(r0 + lr, rows - 1);
  const unsigned short* xsrc = Xb + (size_t)xrow * K + lc * 8;
  const unsigned short* wsrc = Wt + (size_t)(n0 + lr) * K + lc * 8;

  f32x4 acc[4];
#pragma unroll
  for (int t = 0; t < 4; ++t) acc[t] = (f32x4){0.f, 0.f, 0.f, 0.f};

  for (int k0 = 0; k0 < K; k0 += 64) {
    __syncthreads();
    *(uint4*)&sX[lr][lc * 8]      = *(const uint4*)(xsrc + k0);
    *(uint4*)&sX[lr][lc * 8 + 32] = *(const uint4*)(xsrc + k0 + 32);
    *(uint4*)&sW[lr][lc * 8]      = *(const uint4*)(wsrc + k0);
    *(uint4*)&sW[lr][lc * 8 + 32] = *(const uint4*)(wsrc + k0 + 32);
    __syncthreads();
    const bf16x8 aX0 = *(const bf16x8*)&sX[w * 16 + col][quad * 8];
    const bf16x8 aX1 = *(const bf16x8*)&sX[w * 16 + col][32 + quad * 8];
#pragma unroll
    for (int t = 0; t < 4; ++t) {
      const bf16x8 bW0 = *(const bf16x8*)&sW[t * 16 + col][quad * 8];
      const bf16x8 bW1 = *(const bf16x8*)&sW[t * 16 + col][32 + quad * 8];
      acc[t] = __builtin_amdgcn_mfma_f32_16x16x32_bf16(aX0, bW0, acc[t], 0, 0, 0);
      acc[t] = __builtin_amdgcn_mfma_f32_16x16x32_bf16(aX1, bW1, acc[t], 0, 0, 0);
    }
  }
  const int gr_base = r0 + w * 16 + quad * 4;
#pragma unroll
  for (int t = 0; t < 4; ++t) {
    const int n = n0 + t * 16 + col;
    const float bv = bias ? bias[n] : 0.f;
#pragma unroll
    for (int r = 0; r < 4; ++r) {
      const int gr = gr_base + r;
      if (gr < rows) {
        float v = acc[t][r] + bv;
        if (ACT) v = gelu_f(v);
        if (RES) v += res[(size_t)gr * N + n];
        if (OBF) ((unsigned short*)outp)[(size_t)gr * N + n] = f2bf(v);
        else     ((float*)outp)[(size_t)gr * N + n] = v;
      }
    }
  }
}

// ---------------------------------------------------------------------------
// R20: bf16 MFMA GEMM, 64x128 tile (full 128-wide row per block), N=128,
// with FUSED LayerNorm epilogue (+ optional gamma, + optional raw-x out).
// Replaces proj-GEMM + ln_rows and mlp2-GEMM + next-layer ln_rows:
// 9 launches and the x round-trip removed. Row = (quad, r); its 128 cols
// live in 16 lanes (col) x 8 t-tiles -> xor-shuffle masks 1,2,4,8 reduce
// within the col group.
// ---------------------------------------------------------------------------
template<int DOLN, int GAMMA, int WRITEX>
__global__ __launch_bounds__(256) void mgemm_ln_k(
    const unsigned short* __restrict__ Xb, const unsigned short* __restrict__ Wt,
    const float* __restrict__ bias, const float* __restrict__ res,
    const float* __restrict__ lng, const float* __restrict__ lnb,
    const float* __restrict__ gw, const float* __restrict__ gb,
    float* __restrict__ xout, float* __restrict__ h,
    unsigned short* __restrict__ hb, float* __restrict__ gamout,
    int rows, int K)
{
  __shared__ unsigned short sX[64][72];
  __shared__ unsigned short sW[128][72];
  const int tid = threadIdx.x;
  const int w = tid >> 6, lane = tid & 63;
  const int col = lane & 15, quad = lane >> 4;
  const int r0 = blockIdx.x * 64;

  f32x4 acc[8];
#pragma unroll
  for (int t = 0; t < 8; ++t) acc[t] = (f32x4){0.f, 0.f, 0.f, 0.f};

  for (int k0 = 0; k0 < K; k0 += 64) {
    __syncthreads();
#pragma unroll
    for (int l = 0; l < 2; ++l) {
      const int idx = l * 256 + tid;
      const int row = idx >> 3, c = idx & 7;
      const int xrow = min(r0 + row, rows - 1);
      *(uint4*)&sX[row][c * 8] = *(const uint4*)(Xb + (size_t)xrow * K + k0 + c * 8);
    }
#pragma unroll
    for (int l = 0; l < 4; ++l) {
      const int idx = l * 256 + tid;
      const int row = idx >> 3, c = idx & 7;
      *(uint4*)&sW[row][c * 8] = *(const uint4*)(Wt + (size_t)row * K + k0 + c * 8);
    }
    __syncthreads();
    const bf16x8 aX0 = *(const bf16x8*)&sX[w * 16 + col][quad * 8];
    const bf16x8 aX1 = *(const bf16x8*)&sX[w * 16 + col][32 + quad * 8];
#pragma unroll
    for (int t = 0; t < 8; ++t) {
      const bf16x8 bW0 = *(const bf16x8*)&sW[t * 16 + col][quad * 8];
      const bf16x8 bW1 = *(const bf16x8*)&sW[t * 16 + col][32 + quad * 8];
      acc[t] = __builtin_amdgcn_mfma_f32_16x16x32_bf16(aX0, bW0, acc[t], 0, 0, 0);
      acc[t] = __builtin_amdgcn_mfma_f32_16x16x32_bf16(aX1, bW1, acc[t], 0, 0, 0);
    }
  }

  // ---- epilogue: v = acc + bias + res; optional raw write; optional LN ----
  const int gr_base = r0 + w * 16 + quad * 4;
  float bv[8];
#pragma unroll
  for (int t = 0; t < 8; ++t) bv[t] = bias[t * 16 + col];
  float val[8][4];
#pragma unroll
  for (int r = 0; r < 4; ++r) {
    const int grc = min(gr_base + r, rows - 1);
#pragma unroll
    for (int t = 0; t < 8; ++t)
      val[t][r] = acc[t][r] + bv[t] + res[(size_t)grc * DIMC + t * 16 + col];
  }
  if (WRITEX) {
#pragma unroll
    for (int r = 0; r < 4; ++r) {
      const int gr = gr_base + r;
      if (gr < rows) {
#pragma unroll
        for (int t = 0; t < 8; ++t)
          xout[(size_t)gr * DIMC + t * 16 + col] = val[t][r];
      }
    }
  }
  if (DOLN) {
    float lg[8], lb[8], gwa[8], gwb[8];
#pragma unroll
    for (int t = 0; t < 8; ++t) {
      lg[t] = lng[t * 16 + col];
      lb[t] = lnb[t * 16 + col];
      if (GAMMA) { gwa[t] = gw[2 * (t * 16 + col)]; gwb[t] = gw[2 * (t * 16 + col) + 1]; }
    }
#pragma unroll
    for (int r = 0; r < 4; ++r) {
      const int gr = gr_base + r;
      float s = 0.f;
#pragma unroll
      for (int t = 0; t < 8; ++t) s += val[t][r];
      s += __shfl_xor(s, 1); s += __shfl_xor(s, 2);
      s += __shfl_xor(s, 4); s += __shfl_xor(s, 8);
      const float mean = s * (1.f / 128.f);
      float vv = 0.f;
#pragma unroll
      for (int t = 0; t < 8; ++t) { const float d = val[t][r] - mean; vv += d * d; }
      vv += __shfl_xor(vv, 1); vv += __shfl_xor(vv, 2);
      vv += __shfl_xor(vv, 4); vv += __shfl_xor(vv, 8);
      const float inv = rsqrtf(vv * (1.f / 128.f) + 1e-5f);
      float a0 = 0.f, a1 = 0.f;
#pragma unroll
      for (int t = 0; t < 8; ++t) {
        const float o = (val[t][r] - mean) * inv * lg[t] + lb[t];
        if (gr < rows) {
          h[(size_t)gr * DIMC + t * 16 + col] = o;
          hb[(size_t)gr * DIMC + t * 16 + col] = f2bf(o);
        }
        if (GAMMA) { a0 = fmaf(o, gwa[t], a0); a1 = fmaf(o, gwb[t], a1); }
      }
      if (GAMMA) {
        a0 += __shfl_xor(a0, 1); a0 += __shfl_xor(a0, 2);
        a0 += __shfl_xor(a0, 4); a0 += __shfl_xor(a0, 8);
        a1 += __shfl_xor(a1, 1); a1 += __shfl_xor(a1, 2);
        a1 += __shfl_xor(a1, 4); a1 += __shfl_xor(a1, 8);
        if (col == 0 && gr < rows) {
          gamout[(size_t)gr * 2 + 0] = expf(a0 + gb[0]);
          gamout[(size_t)gr * 2 + 1] = expf(a1 + gb[1]);
        }
      }
    }
  }
}

// ---------------------------------------------------------------------------
// bf16 MFMA GEMM, 128x128 tile (QKV), with fused V-transpose epilogue
// ---------------------------------------------------------------------------
template<int OBF, int VT>
__global__ __launch_bounds__(256) void mgemm128_k(
    const unsigned short* __restrict__ Xb, const unsigned short* __restrict__ Wt,
    const float* __restrict__ bias, void* __restrict__ outp,
    unsigned short* __restrict__ vtp, int rows, int K, int N)
{
  __shared__ unsigned short sX[128][72];
  __shared__ unsigned short sW[128][72];
  const int tid = threadIdx.x;
  const int w = tid >> 6, lane = tid & 63;
  const int col = lane & 15, quad = lane >> 4;
  const int wr = w >> 1, wc = w & 1;
  const int r0 = blockIdx.x * 128, n0 = blockIdx.y * 128;

  f32x4 acc[4][4];
#pragma unroll
  for (int i = 0; i < 4; ++i)
#pragma unroll
    for (int j = 0; j < 4; ++j) acc[i][j] = (f32x4){0.f, 0.f, 0.f, 0.f};

  for (int k0 = 0; k0 < K; k0 += 64) {
    __syncthreads();
#pragma unroll
    for (int l = 0; l < 4; ++l) {
      const int idx = l * 256 + tid;
      const int row = idx >> 3, c = idx & 7;
      const int xrow = min(r0 + row, rows - 1);
      *(uint4*)&sX[row][c * 8] = *(const uint4*)(Xb + (size_t)xrow * K + k0 + c * 8);
      *(uint4*)&sW[row][c * 8] = *(const uint4*)(Wt + (size_t)(n0 + row) * K + k0 + c * 8);
    }
    __syncthreads();
    bf16x8 aX[4][2];
#pragma unroll
    for (int i = 0; i < 4; ++i) {
      aX[i][0] = *(const bf16x8*)&sX[wr * 64 + i * 16 + col][quad * 8];
      aX[i][1] = *(const bf16x8*)&sX[wr * 64 + i * 16 + col][32 + quad * 8];
    }
#pragma unroll
    for (int j = 0; j < 4; ++j) {
      const bf16x8 b0 = *(const bf16x8*)&sW[wc * 64 + j * 16 + col][quad * 8];
      const bf16x8 b1 = *(const bf16x8*)&sW[wc * 64 + j * 16 + col][32 + quad * 8];
#pragma unroll
      for (int i = 0; i < 4; ++i) {
        acc[i][j] = __builtin_amdgcn_mfma_f32_16x16x32_bf16(aX[i][0], b0, acc[i][j], 0, 0, 0);
        acc[i][j] = __builtin_amdgcn_mfma_f32_16x16x32_bf16(aX[i][1], b1, acc[i][j], 0, 0, 0);
      }
    }
  }
  const bool dovt = VT && (n0 >= 2048);
#pragma unroll
  for (int i = 0; i < 4; ++i) {
    const int gr_base = r0 + wr * 64 + i * 16 + quad * 4;
    int bb[4], mm[4];
    if (dovt) {
#pragma unroll
      for (int r = 0; r < 4; ++r) {
        const int gr = gr_base + r;
        bb[r] = gr / 1025;
        mm[r] = gr - bb[r] * 1025;
      }
    }
#pragma unroll
    for (int j = 0; j < 4; ++j) {
      const int n = n0 + wc * 64 + j * 16 + col;
      const float bv = bias ? bias[n] : 0.f;
      const int hh = (n - 2048) >> 7;
      const int d  = (n - 2048) & 127;
#pragma unroll
      for (int r = 0; r < 4; ++r) {
        const int gr = gr_base + r;
        if (gr < rows) {
          const float v = acc[i][j][r] + bv;
          const unsigned short bf = f2bf(v);
          if (OBF) ((unsigned short*)outp)[(size_t)gr * N + n] = bf;
          else     ((float*)outp)[(size_t)gr * N + n] = v;
          if (dovt) vtp[(((size_t)(bb[r] * NHEADS + hh) * DIMC + d) * ACS) + mm[r]] = bf;
        }
      }
    }
  }
}

// ---------------------------------------------------------------------------
// Wave-per-row LayerNorm; optional bf16 shadow out; optional fused gamma
// (only used once now: initial ln1 after the PE encoder)
// ---------------------------------------------------------------------------
__global__ __launch_bounds__(256) void ln_rows_k(
    const float* __restrict__ in, float* __restrict__ out,
    unsigned short* __restrict__ outb,
    const float* __restrict__ g, const float* __restrict__ b,
    const float* __restrict__ gw, const float* __restrict__ gb,
    float* __restrict__ gamout, int rows, int D)
{
  const int wv = (blockIdx.x * blockDim.x + threadIdx.x) >> 6;
  const int lane = threadIdx.x & 63;
  if (wv >= rows) return;
  const float* r = in + (size_t)wv * D;
  float s = 0.f;
  for (int d = lane; d < D; d += 64) s += r[d];
  for (int off = 32; off; off >>= 1) s += __shfl_down(s, off);
  const float mean = __shfl(s, 0) / (float)D;
  float v = 0.f;
  for (int d = lane; d < D; d += 64) { float t = r[d] - mean; v += t * t; }
  for (int off = 32; off; off >>= 1) v += __shfl_down(v, off);
  const float inv = rsqrtf(__shfl(v, 0) / (float)D + 1e-5f);
  float* orow = out + (size_t)wv * D;
  float a0 = 0.f, a1 = 0.f;
  for (int d = lane; d < D; d += 64) {
    const float o = (r[d] - mean) * inv * g[d] + b[d];
    orow[d] = o;
    if (outb) outb[(size_t)wv * D + d] = f2bf(o);
    if (gw) { a0 = fmaf(o, gw[2 * d], a0); a1 = fmaf(o, gw[2 * d + 1], a1); }
  }
  if (gw) {
    for (int off = 32; off; off >>= 1) { a0 += __shfl_down(a0, off); a1 += __shfl_down(a1, off); }
    if (lane == 0) {
      gamout[(size_t)wv * 2 + 0] = expf(a0 + gb[0]);
      gamout[(size_t)wv * 2 + 1] = expf(a1 + gb[1]);
    }
  }
}

// ---------------------------------------------------------------------------
// prep: bit-packed adj_cls
// ---------------------------------------------------------------------------
__global__ __launch_bounds__(256) void adjp_k(const float* __restrict__ adj,
                                              unsigned long long* __restrict__ adjp)
{
  const int n = blockIdx.x;
  const int b = blockIdx.y;
  const int wv = threadIdx.x >> 6, lane = threadIdx.x & 63;
  for (int w = wv; w < 17; w += 4) {
    const int m = w * 64 + lane;
    float av = 0.f;
    if (n == 0) av = (m == 0) ? 1.f : 0.f;
    else if (m >= 1 && m <= NSEQ) av = adj[((size_t)b * NSEQ + (n - 1)) * NSEQ + (m - 1)];
    const unsigned long long mask = __ballot(av != 0.f);
    if (lane == 0) adjp[((size_t)b * M_ + n) * 17 + w] = mask;
  }
}

// ---------------------------------------------------------------------------
// prep: Wt[n][k] = bf16(W[k][n])
// ---------------------------------------------------------------------------
__global__ void wtrans_k(const float* __restrict__ W, unsigned short* __restrict__ Wt,
                         int K, int N)
{
  __shared__ float t[32][33];
  const int k0 = blockIdx.x * 32, n0 = blockIdx.y * 32;
  const float* Wd = W + (size_t)blockIdx.z * K * N;
  unsigned short* Wtd = Wt + (size_t)blockIdx.z * K * N;
  for (int i = threadIdx.y; i < 32; i += 8)
    t[i][threadIdx.x] = Wd[(size_t)(k0 + i) * N + n0 + threadIdx.x];
  __syncthreads();
  for (int i = threadIdx.y; i < 32; i += 8)
    Wtd[(size_t)(n0 + i) * K + k0 + threadIdx.x] = f2bf(t[threadIdx.x][i]);
}

// ---------------------------------------------------------------------------
// bf16 MFMA flash attention, 8-wave blocks (512 thr).
// Q-tile 256 (32 q-rows/wave, 2 row-groups). Grid (8 heads, 4 q-tiles,
// 8 batch) = 256 blocks = 1/CU. Each bK/bV LDS fragment read feeds TWO
// MFMAs. Single barrier per tile, full-tile-ahead DMA prefetch.
// ---------------------------------------------------------------------------
__global__ __launch_bounds__(512) void attn_mfma_k(
    const unsigned short* __restrict__ qkv, const float* __restrict__ gamma,
    const unsigned long long* __restrict__ adjp, const unsigned short* __restrict__ vt,
    unsigned short* __restrict__ o)
{
  __shared__ unsigned short sK[2][64][128];   // keys, linear rows (DMA dest), 32K
  __shared__ unsigned short sVt[2][128][64];  // transposed V (DMA dest), 32K
  __shared__ unsigned short sP[256][64];      // P; wave w owns rows 32w..32w+31, 32K

  const int hh = blockIdx.x, qt = blockIdx.y, b = blockIdx.z;
  const int tid = threadIdx.x;
  const int w = tid >> 6;                  // 0..7
  const int lane = tid & 63;
  const int col = lane & 15;
  const int quad = lane >> 4;
  const int qbase = qt * 256 + w * 32;     // <= 992; all q-rows valid
  const float scale = 0.088388347648318447f;  // 128^-0.5

  // Q fragments (registers, direct global), 2 row-groups
  bf16x8 aQ[2][4];
#pragma unroll
  for (int rg = 0; rg < 2; ++rg) {
    const int qrow = qbase + rg * 16 + col;
    const unsigned short* qp = qkv + ((size_t)(b * M_ + qrow)) * QKV3 + hh * DIMC + quad * 8;
#pragma unroll
    for (int c = 0; c < 4; ++c) aQ[rg][c] = *(const bf16x8*)(qp + c * 32);
  }
  float g0[2][4], g1[2][4];
  int adjo[2][4];
#pragma unroll
  for (int rg = 0; rg < 2; ++rg)
#pragma unroll
    for (int r = 0; r < 4; ++r) {
      const int nc = qbase + rg * 16 + quad * 4 + r;
      g0[rg][r] = gamma[(size_t)(b * M_ + nc) * 2 + 0] * scale;
      g1[rg][r] = gamma[(size_t)(b * M_ + nc) * 2 + 1];
      adjo[rg][r] = (b * M_ + nc) * 17;
    }

  float l_i[2][4] = {{0.f, 0.f, 0.f, 0.f}, {0.f, 0.f, 0.f, 0.f}};
  f32x4 Oacc[2][8];
#pragma unroll
  for (int rg = 0; rg < 2; ++rg)
#pragma unroll
    for (int t = 0; t < 8; ++t) Oacc[rg][t] = (f32x4){0.f, 0.f, 0.f, 0.f};

  const size_t vtbase = ((size_t)(b * NHEADS + hh)) * DIMC * ACS;

  // DMA staging helpers. LDS dest is wave-uniform base + lane*16B (linear);
  // the bank-conflict swizzle is applied to the GLOBAL source chunk instead.
  auto stageK = [&](int buf, int kt_) {
#pragma unroll
    for (int l = 0; l < 2; ++l) {
      const int m = l * 32 + w * 4 + (lane >> 4);          // row within tile
      const int gm = min(kt_ * 64 + m, 1024);              // clamp (masked later)
      const unsigned short* src = qkv + ((size_t)(b * M_ + gm)) * QKV3 + 1024
                                  + hh * DIMC + (((lane & 15) ^ (m & 7)) * 8);
      g2lds16(src, &sK[buf][l * 32 + w * 4][0]);
    }
  };
  auto stageV = [&](int buf, int kt_) {
#pragma unroll
    for (int l = 0; l < 2; ++l) {
      const int d = l * 64 + w * 8 + (lane >> 3);          // head-dim row
      const unsigned short* src = vt + vtbase + (size_t)d * ACS + kt_ * 64
                                  + (((lane & 7) ^ (d & 7)) * 8);
      g2lds16(src, &sVt[buf][l * 64 + w * 8][0]);
    }
  };

  // prologue: tile-0 K and V DMAs in flight
  stageK(0, 0);
  stageV(0, 0);

  int cur = 0;
  for (int kt = 0; kt < 17; ++kt) {
    const int m0 = kt * 64;
    // Own tile-kt DMAs (issued a full tile ago) must land; one raw barrier
    // publishes all waves' DMA writes. No mid-tile barrier (sP is own-wave).
    asm volatile("s_waitcnt vmcnt(0)" ::: "memory");
    __builtin_amdgcn_s_barrier();
    __builtin_amdgcn_sched_barrier(0);   // keep this tile's LDS reads below

    const bool more = (kt < 16);
    if (more) {
      stageK(cur ^ 1, kt + 1);
      stageV(cur ^ 1, kt + 1);
    }

    // current tile's adj masks — L2-resident, latency hides under QK MFMAs
    unsigned long long mk[2][4];
#pragma unroll
    for (int rg = 0; rg < 2; ++rg)
#pragma unroll
      for (int r = 0; r < 4; ++r) mk[rg][r] = adjp[adjo[rg][r] + kt];

    // S = Q K^T from sK[cur]; each bK read feeds both row-groups
    f32x4 Sacc[2][4];
#pragma unroll
    for (int rg = 0; rg < 2; ++rg)
#pragma unroll
      for (int t = 0; t < 4; ++t) Sacc[rg][t] = (f32x4){0.f, 0.f, 0.f, 0.f};
    __builtin_amdgcn_s_setprio(1);
#pragma unroll
    for (int t = 0; t < 4; ++t) {
#pragma unroll
      for (int c = 0; c < 4; ++c) {
        const bf16x8 bK = *(const bf16x8*)&sK[cur][t * 16 + col][((c * 4 + quad) ^ (col & 7)) * 8];
        Sacc[0][t] = __builtin_amdgcn_mfma_f32_16x16x32_bf16(aQ[0][c], bK, Sacc[0][t], 0, 0, 0);
        Sacc[1][t] = __builtin_amdgcn_mfma_f32_16x16x32_bf16(aQ[1][c], bK, Sacc[1][t], 0, 0, 0);
      }
    }
    __builtin_amdgcn_s_setprio(0);

    // p = exp(g0*S + (bit ? g1 : 0)); write P to LDS (own-wave rows), acc l
#pragma unroll
    for (int t = 0; t < 4; ++t) {
      const int m = m0 + t * 16 + col;
      const bool mv = (m < M_);
      const int chb = t * 2 + (col >> 3);
      const int sh = t * 16 + col;
#pragma unroll
      for (int rg = 0; rg < 2; ++rg)
#pragma unroll
        for (int r = 0; r < 4; ++r) {
          const float bias = ((mk[rg][r] >> sh) & 1ull) ? g1[rg][r] : 0.f;
          const float s = fmaf(g0[rg][r], Sacc[rg][t][r], bias);
          const float pv = mv ? __expf(s) : 0.f;
          l_i[rg][r] += pv;
          const int ql = w * 32 + rg * 16 + quad * 4 + r;
          sP[ql][((chb ^ (ql & 7)) * 8) + (col & 7)] = f2bf(pv);
        }
    }

    // O += P V; each bV read feeds both row-groups. No barrier: sP is
    // same-wave (lgkmcnt-ordered), sVt[cur] published by tile-top barrier.
    __builtin_amdgcn_s_setprio(1);
#pragma unroll
    for (int ch = 0; ch < 2; ++ch) {
      const int pr = w * 32 + col;          // (pr&7)==(pr+16)&7==(col&7)
      const bf16x8 aP0 = *(const bf16x8*)&sP[pr][((ch * 4 + quad) ^ (col & 7)) * 8];
      const bf16x8 aP1 = *(const bf16x8*)&sP[pr + 16][((ch * 4 + quad) ^ (col & 7)) * 8];
#pragma unroll
      for (int t = 0; t < 8; ++t) {
        const bf16x8 bV = *(const bf16x8*)&sVt[cur][t * 16 + col][((ch * 4 + quad) ^ (col & 7)) * 8];
        Oacc[0][t] = __builtin_amdgcn_mfma_f32_16x16x32_bf16(aP0, bV, Oacc[0][t], 0, 0, 0);
        Oacc[1][t] = __builtin_amdgcn_mfma_f32_16x16x32_bf16(aP1, bV, Oacc[1][t], 0, 0, 0);
      }
    }
    __builtin_amdgcn_s_setprio(0);
    cur ^= 1;
  }

  // epilogue: reduce l across the 16-lane col group, O /= l, bf16 out
#pragma unroll
  for (int rg = 0; rg < 2; ++rg)
#pragma unroll
    for (int r = 0; r < 4; ++r) {
      float s = l_i[rg][r];
      s += __shfl_xor(s, 1);
      s += __shfl_xor(s, 2);
      s += __shfl_xor(s, 4);
      s += __shfl_xor(s, 8);
      const int n = qbase + rg * 16 + quad * 4 + r;   // <= 1023, always valid
      const float invl = 1.f / s;
      unsigned short* orow = o + ((size_t)(b * M_ + n)) * (NHEADS * DIMC) + hh * DIMC + col;
#pragma unroll
      for (int t = 0; t < 8; ++t) orow[t * 16] = f2bf(Oacc[rg][t][r] * invl);
    }
}

// ---------------------------------------------------------------------------
// Attention for the single leftover q-row (n = 1024), one block per (b,hh).
// ---------------------------------------------------------------------------
__global__ __launch_bounds__(256) void cls_attn_k(
    const unsigned short* __restrict__ qkv, const float* __restrict__ gamma,
    const unsigned long long* __restrict__ adjp, const unsigned short* __restrict__ vt,
    unsigned short* __restrict__ o)
{
  __shared__ float qf[DIMC];
  __shared__ float pbuf[1056];
  __shared__ float lred[4];
  __shared__ float oshare[DIMC];
  const int hh = blockIdx.x & 7, b = blockIdx.x >> 3;
  const int tid = threadIdx.x;
  const size_t rowbase = (size_t)b * M_ + 1024;

  if (tid < DIMC) qf[tid] = bf2f(qkv[rowbase * QKV3 + hh * DIMC + tid]);
  __syncthreads();
  const float g0 = gamma[rowbase * 2 + 0] * 0.088388347648318447f;
  const float g1 = gamma[rowbase * 2 + 1];

  float lpart = 0.f;
  for (int m = tid; m < M_; m += 256) {
    const unsigned short* kp = qkv + ((size_t)(b * M_ + m)) * QKV3 + 1024 + hh * DIMC;
    float s = 0.f;
#pragma unroll
    for (int d0 = 0; d0 < DIMC; d0 += 8) {
      const bf16x8 kv = *(const bf16x8*)(kp + d0);
#pragma unroll
      for (int j = 0; j < 8; ++j)
        s = fmaf(bf2f((unsigned short)kv[j]), qf[d0 + j], s);
    }
    const unsigned long long mkv = adjp[rowbase * 17 + (m >> 6)];
    const float bias = ((mkv >> (m & 63)) & 1ull) ? g1 : 0.f;
    const float p = __expf(fmaf(g0, s, bias));
    pbuf[m] = p;
    lpart += p;
  }
  for (int off = 32; off; off >>= 1) lpart += __shfl_down(lpart, off);
  if ((tid & 63) == 0) lred[tid >> 6] = lpart;
  __syncthreads();
  const float linv = 1.f / (lred[0] + lred[1] + lred[2] + lred[3]);

  const int d = tid & 127, half = tid >> 7;
  const unsigned short* vrow = vt + ((size_t)(b * NHEADS + hh)) * DIMC * ACS + (size_t)d * ACS;
  float acc = 0.f;
  const int mstart = half * 512;
  const int mend = half ? 1024 : 512;       // half1 tail m=1024 handled below
  for (int m0 = mstart; m0 < mend; m0 += 8) {
    const bf16x8 vv = *(const bf16x8*)(vrow + m0);
#pragma unroll
    for (int j = 0; j < 8; ++j)
      acc = fmaf(bf2f((unsigned short)vv[j]), pbuf[m0 + j], acc);
  }
  if (half) acc = fmaf(bf2f(vrow[1024]), pbuf[1024], acc);
  if (half == 0) oshare[d] = acc;
  __syncthreads();
  if (half == 1) {
    const float val = (oshare[d] + acc) * linv;
    o[rowbase * (NHEADS * DIMC) + hh * DIMC + d] = f2bf(val);
  }
}

// ---------------------------------------------------------------------------
// Head stage: out[8][128] = (optional LN)(in) @ W(128x128) + bias, opt gelu.
// grid 8 blocks x 256 thr; block computes 16 cols x 8 rows, 2-way k-split.
// ---------------------------------------------------------------------------
template<int DOLN, int ACT>
__global__ __launch_bounds__(256) void hstage_k(
    const float* __restrict__ in, int in_stride,
    const float* __restrict__ lng, const float* __restrict__ lnb,
    const float* __restrict__ W, const float* __restrict__ bias,
    float* __restrict__ out)
{
  __shared__ float xn[8][128];
  __shared__ float red[128];
  const int tid = threadIdx.x;
  for (int i = tid; i < 1024; i += 256) {
    const int r = i >> 7, d = i & 127;
    xn[r][d] = in[(size_t)r * in_stride + d];
  }
  __syncthreads();
  if (DOLN) {
    // wave wv: lanes 0-31 handle row 2wv, lanes 32-63 handle row 2wv+1
    const int wv = tid >> 6, lane = tid & 63;
    const int row = wv * 2 + (lane >> 5);
    const int l32 = lane & 31;
    float s = 0.f;
    for (int d = l32; d < 128; d += 32) s += xn[row][d];
    for (int off = 16; off; off >>= 1) s += __shfl_xor(s, off);
    const float mean = s * (1.f / 128.f);
    float v = 0.f;
    for (int d = l32; d < 128; d += 32) { const float t = xn[row][d] - mean; v += t * t; }
    for (int off = 16; off; off >>= 1) v += __shfl_xor(v, off);
    const float inv = rsqrtf(v * (1.f / 128.f) + 1e-5f);
    for (int d = l32; d < 128; d += 32)
      xn[row][d] = (xn[row][d] - mean) * inv * lng[d] + lnb[d];
    __syncthreads();
  }
  const int col = blockIdx.x * 16 + (tid & 15);
  const int row = (tid >> 4) & 7;
  const int ks = tid >> 7;                 // k-split: 0 -> [0,64), 1 -> [64,128)
  float acc = 0.f;
  const int kb = ks * 64;
  for (int k = kb; k < kb + 64; ++k)
    acc = fmaf(xn[row][k], W[k * 128 + col], acc);
  if (ks) red[tid - 128] = acc;
  __syncthreads();
  if (!ks) {
    float v = acc + red[tid] + bias[col];
    if (ACT) v = gelu_f(v);
    out[row * 128 + col] = v;
  }
}

// ---------------------------------------------------------------------------
// Head final: out_p[8][1000] = LN(in) @ pw4 + pb4.
// grid 32 blocks (8 rows x 4 col-chunks of 250) x 256 thr.
// ---------------------------------------------------------------------------
__global__ __launch_bounds__(256) void hfinal_k(
    const float* __restrict__ in,
    const float* __restrict__ plg, const float* __restrict__ plb,
    const float* __restrict__ W, const float* __restrict__ bias,
    float* __restrict__ out_p)
{
  __shared__ float xn[128];
  const int r = blockIdx.x & 7, cc = blockIdx.x >> 3;
  const int tid = threadIdx.x;
  const int lane = tid & 63;
  // each wave redundantly reduces row r (lane covers 2 elems)
  const float a = in[r * 128 + lane];
  const float b = in[r * 128 + 64 + lane];
  float s = a + b;
  for (int off = 32; off; off >>= 1) s += __shfl_xor(s, off);
  const float mean = s * (1.f / 128.f);
  const float t0 = a - mean, t1 = b - mean;
  float v = t0 * t0 + t1 * t1;
  for (int off = 32; off; off >>= 1) v += __shfl_xor(v, off);
  const float inv = rsqrtf(v * (1.f / 128.f) + 1e-5f);
  if (tid < 128) xn[tid] = (in[r * 128 + tid] - mean) * inv * plg[tid] + plb[tid];
  __syncthreads();
  const int col = cc * 250 + tid;
  if (tid < 250) {
    float acc = bias[col];
    for (int k = 0; k < 128; ++k)
      acc = fmaf(xn[k], W[(size_t)k * 1000 + col], acc);
    out_p[r * 1000 + col] = acc;
  }
}

// ---------------------------------------------------------------------------
__global__ void fill_cls_k(const float* __restrict__ cls, float* __restrict__ x)
{
  x[(size_t)blockIdx.x * M_ * DIMC + threadIdx.x] = cls[threadIdx.x];
}

// ---------------------------------------------------------------------------
extern "C" void kernel_launch(void* const* d_in, const int* in_sizes, int n_in,
                              void* d_out, int out_size, void* d_ws, size_t ws_size,
                              hipStream_t stream)
{
  (void)in_sizes; (void)n_in; (void)out_size; (void)ws_size;
  const float* node_feat = (const float*)d_in[0];
  const float* adj       = (const float*)d_in[1];
  const float* lapl      = (const float*)d_in[2];
  const float* cls_token = (const float*)d_in[3];
  const float* pe_w1 = (const float*)d_in[4];
  const float* pe_b1 = (const float*)d_in[5];
  const float* pe_w2 = (const float*)d_in[6];
  const float* pe_b2 = (const float*)d_in[7];
  const float* pe_w3 = (const float*)d_in[8];
  const float* pe_b3 = (const float*)d_in[9];
  const float* pe_lng = (const float*)d_in[10];
  const float* pe_lnb = (const float*)d_in[11];
  const float* pe_w4 = (const float*)d_in[12];
  const float* pe_b4 = (const float*)d_in[13];
  const float* blk_ln1_g = (const float*)d_in[14];
  const float* blk_ln1_b = (const float*)d_in[15];
  const float* blk_qkv_w = (const float*)d_in[16];
  const float* blk_proj_w = (const float*)d_in[17];
  const float* blk_proj_b = (const float*)d_in[18];
  const float* blk_gamma_w = (const float*)d_in[19];
  const float* blk_gamma_b = (const float*)d_in[20];
  const float* blk_ln2_g = (const float*)d_in[21];
  const float* blk_ln2_b = (const float*)d_in[22];
  const float* blk_mlp_w1 = (const float*)d_in[23];
  const float* blk_mlp_b1 = (const float*)d_in[24];
  const float* blk_mlp_w2 = (const float*)d_in[25];
  const float* blk_mlp_b2 = (const float*)d_in[26];
  const float* head_lng = (const float*)d_in[27];
  const float* head_lnb = (const float*)d_in[28];
  const float* head_w = (const float*)d_in[29];
  const float* head_b = (const float*)d_in[30];
  const float* proj_w1 = (const float*)d_in[31];
  const float* proj_b1 = (const float*)d_in[32];
  const float* proj_w2 = (const float*)d_in[33];
  const float* proj_b2 = (const float*)d_in[34];
  const float* proj_w3 = (const float*)d_in[35];
  const float* proj_b3 = (const float*)d_in[36];
  const float* proj_lng = (const float*)d_in[37];
  const float* proj_lnb = (const float*)d_in[38];
  const float* proj_w4 = (const float*)d_in[39];
  const float* proj_b4 = (const float*)d_in[40];

  // ---- workspace layout ----
  float* ws   = (float*)d_ws;
  float* x    = ws;                        // 1,049,600 f
  float* h    = x + 1049600;               // 1,049,600 f
  float* gam  = h + 1049600;               // 16,400 f
  float* obuf = gam + 16400;               // 5,248,000 f region
  unsigned short* obufb = (unsigned short*)obuf;             // 8200*1024 bf16
  unsigned short* hidb  = (unsigned short*)(obuf + 4198400); // 8200*256 bf16
  float* sm  = obuf + 5248000;             // 8,192 f (head scratch p1/p2)
  unsigned short* hb   = (unsigned short*)(sm + 8192);       // 8200*128 bf16
  unsigned short* qkv  = hb + 1049600;     // 25,190,400 us
  unsigned long long* adjp = (unsigned long long*)(qkv + 25190400);  // 139,400 u64
  unsigned short* vt   = (unsigned short*)(adjp + 139400 + 88);      // 8,912,896 us
  unsigned short* qkvWt = vt + 8912896;    // 5*393216
  unsigned short* projWt = qkvWt + 5 * 393216;
  unsigned short* mlp1Wt = projWt + 5 * 131072;
  unsigned short* mlp2Wt = mlp1Wt + 5 * 32768;

  float* out_c = (float*)d_out;            // (8,128)
  float* out_p = out_c + NB * DIMC;        // (8,1000)
  float* p1 = sm;                          // 1024 f
  float* p2 = sm + 1024;                   // 1024 f

  // ---- prep ----
  adjp_k<<<dim3(M_, NB), 256, 0, stream>>>(adj, adjp);
  wtrans_k<<<dim3(4, 96, 5), dim3(32, 8), 0, stream>>>(blk_qkv_w, qkvWt, 128, 3072);
  wtrans_k<<<dim3(32, 4, 5), dim3(32, 8), 0, stream>>>(blk_proj_w, projWt, 1024, 128);
  wtrans_k<<<dim3(4, 8, 5), dim3(32, 8), 0, stream>>>(blk_mlp_w1, mlp1Wt, 128, 256);
  wtrans_k<<<dim3(8, 4, 5), dim3(32, 8), 0, stream>>>(blk_mlp_w2, mlp2Wt, 256, 128);

  // ---- PE encoder ----
  pe_fused_k<<<512, 128, 0, stream>>>(node_feat, lapl, pe_w1, pe_b1, pe_w2, pe_b2,
                                      pe_w3, pe_b3, pe_lng, pe_lnb, pe_w4, pe_b4, x);
  fill_cls_k<<<NB, DIMC, 0, stream>>>(cls_token, x);

  // ---- initial LN1 (layer 0) ----
  const int lnGrid = (ROWS * 64 + 255) / 256;  // 2050
  ln_rows_k<<<lnGrid, 256, 0, stream>>>(x, h, hb, blk_ln1_g, blk_ln1_b,
                                        blk_gamma_w, blk_gamma_b, gam, ROWS, DIMC);

  // ---- transformer layers (LN fused into proj / mlp2 epilogues) ----
  for (int i = 0; i < 5; ++i) {
    const float* pb   = blk_proj_b + i * DIMC;
    const float* ln2g = blk_ln2_g + i * DIMC;
    const float* ln2b = blk_ln2_b + i * DIMC;
    const float* mb1  = blk_mlp_b1 + i * 256;
    const float* mb2  = blk_mlp_b2 + i * DIMC;
    const unsigned short* qw = qkvWt + (size_t)i * 393216;
    const unsigned short* pw = projWt + (size_t)i * 131072;
    const unsigned short* m1w = mlp1Wt + (size_t)i * 32768;
    const unsigned short* m2w = mlp2Wt + (size_t)i * 32768;

    mgemm128_k<1, 1><<<dim3(65, 24), 256, 0, stream>>>(hb, qw, nullptr, qkv, vt, ROWS, 128, 3072);
    attn_mfma_k<<<dim3(NHEADS, 4, NB), 512, 0, stream>>>(qkv, gam, adjp, vt, obufb);
    cls_attn_k<<<64, 256, 0, stream>>>(qkv, gam, adjp, vt, obufb);

    // proj + LN2 fused: h(in) is ln1-out residual; h/hb(out) = LN2 result
    mgemm_ln_k<1, 0, 0><<<129, 256, 0, stream>>>(
        obufb, pw, pb, h, ln2g, ln2b, nullptr, nullptr,
        nullptr, h, hb, nullptr, ROWS, 1024);

    mgemm_k<1, 1, 0><<<dim3(129, 4), 256, 0, stream>>>(hb, m1w, mb1, nullptr, hidb, ROWS, 128, 256);

    if (i < 4) {
      // mlp2 + next layer's LN1 + gamma fused
      const float* nln1g = blk_ln1_g + (i + 1) * DIMC;
      const float* nln1b = blk_ln1_b + (i + 1) * DIMC;
      const float* ngw   = blk_gamma_w + (size_t)(i + 1) * DIMC * 2;
      const float* ngb   = blk_gamma_b + (i + 1) * 2;
      mgemm_ln_k<1, 1, 0><<<129, 256, 0, stream>>>(
          hidb, m2w, mb2, h, nln1g, nln1b, ngw, ngb,
          nullptr, h, hb, gam, ROWS, 256);
    } else {
      // last layer: raw x for the head, no LN
      mgemm_ln_k<0, 0, 1><<<129, 256, 0, stream>>>(
          hidb, m2w, mb2, h, nullptr, nullptr, nullptr, nullptr,
          x, nullptr, nullptr, nullptr, ROWS, 256);
    }
  }

  // ---- head: 5 parallel stage kernels ----
  hstage_k<1, 0><<<8, 256, 0, stream>>>(x, M_ * DIMC, head_lng, head_lnb,
                                        head_w, head_b, out_c);
  hstage_k<0, 1><<<8, 256, 0, stream>>>(out_c, 128, nullptr, nullptr,
                                        proj_w1, proj_b1, p1);
  hstage_k<0, 1><<<8, 256, 0, stream>>>(p1, 128, nullptr, nullptr,
                                        proj_w2, proj_b2, p2);
  hstage_k<0, 1><<<8, 256, 0, stream>>>(p2, 128, nullptr, nullptr,
                                        proj_w3, proj_b3, p1);
  hfinal_k<<<32, 256, 0, stream>>>(p1, proj_lng, proj_lnb, proj_w4, proj_b4, out_p);
}

// Round 10
// 1326.275 us; speedup vs baseline: 1.0357x; 1.0357x over previous
//
#include <hip/hip_runtime.h>
#include <hip/hip_bf16.h>
#include <math.h>

// Problem constants
#define NB 8
#define NSEQ 1024
#define M_ 1025                 // NSEQ + 1 (cls)
#define ROWS (NB * M_)          // 8200
#define DIMC 128
#define NHEADS 8
#define QKV3 3072               // 3*8*128
#define PEROWS (NB * NSEQ)      // 8192
#define ACS 1088                // vt padded column stride

typedef __attribute__((ext_vector_type(8))) short bf16x8;
typedef __attribute__((ext_vector_type(4))) float f32x4;

__device__ __forceinline__ float gelu_f(float x) {
  return 0.5f * x * (1.f + erff(x * 0.70710678118654752440f));
}

__device__ __forceinline__ unsigned short f2bf(float f) {
  __hip_bfloat16 h = __float2bfloat16(f);
  return *reinterpret_cast<unsigned short*>(&h);
}

__device__ __forceinline__ float bf2f(unsigned short u) {
  union { unsigned int i; float f; } c;
  c.i = ((unsigned int)u) << 16;
  return c.f;
}

// async global->LDS DMA, 16B per lane; LDS dest = wave-uniform base + lane*16
__device__ __forceinline__ void g2lds16(const void* g, void* l) {
  __builtin_amdgcn_global_load_lds(
      (__attribute__((address_space(1))) void*)(g),
      (__attribute__((address_space(3))) void*)(l), 16, 0, 0);
}

// ---------------------------------------------------------------------------
// PE matmul stage (LDS weights, float4 k-groups, capped unroll)
// ---------------------------------------------------------------------------
template<int K, int KP, int C, int SS, int DOGELU>
__device__ __forceinline__ void pe_stage(
    int tid, const float* __restrict__ W, const float* __restrict__ B,
    const float* src, float* dst, float (*wb)[128])
{
  for (int i = tid; i < K * C; i += 128) wb[i / C][i % C] = W[i];
  if (tid < C) {
#pragma unroll
    for (int k = K; k < KP; ++k) wb[k][tid] = 0.f;
  }
  __syncthreads();
  if (tid < C) {
    float acc[16];
#pragma unroll
    for (int r = 0; r < 16; ++r) acc[r] = B[tid];
#pragma unroll 1
    for (int k4 = 0; k4 < KP; k4 += 4) {
      const float w0 = wb[k4 + 0][tid];
      const float w1 = wb[k4 + 1][tid];
      const float w2 = wb[k4 + 2][tid];
      const float w3 = wb[k4 + 3][tid];
#pragma unroll
      for (int r = 0; r < 16; ++r) {
        const float4 av = *(const float4*)&src[r * SS + k4];
        acc[r] = fmaf(av.x, w0, acc[r]);
        acc[r] = fmaf(av.y, w1, acc[r]);
        acc[r] = fmaf(av.z, w2, acc[r]);
        acc[r] = fmaf(av.w, w3, acc[r]);
      }
    }
#pragma unroll
    for (int r = 0; r < 16; ++r) dst[r * 72 + tid] = DOGELU ? gelu_f(acc[r]) : acc[r];
  }
  __syncthreads();
}

// ---------------------------------------------------------------------------
// Fused PE encoder
// ---------------------------------------------------------------------------
__global__ __launch_bounds__(128) void pe_fused_k(
    const float* __restrict__ nf, const float* __restrict__ lp,
    const float* __restrict__ w1, const float* __restrict__ b1,
    const float* __restrict__ w2, const float* __restrict__ b2,
    const float* __restrict__ w3, const float* __restrict__ b3,
    const float* __restrict__ lng, const float* __restrict__ lnb,
    const float* __restrict__ w4, const float* __restrict__ b4,
    float* __restrict__ x)
{
  __shared__ float sIn[16][36];
  __shared__ float sX[16][72];
  __shared__ float sY[16][72];
  __shared__ float wb[72][128];   // staged weights [k][c]
  const int tid = threadIdx.x;
  const int r0 = blockIdx.x * 16;

  for (int i = tid; i < 16 * 35; i += 128) {
    const int r = i / 35, c = i - r * 35;
    const int gr = r0 + r;
    sIn[r][c] = (c < 3) ? nf[(size_t)gr * 3 + c] : lp[(size_t)gr * 32 + (c - 3)];
  }
  if (tid < 16) {
    sIn[tid][35] = 0.f;
    sX[tid][70] = 0.f; sX[tid][71] = 0.f;   // pad cols stay zero forever
    sY[tid][70] = 0.f; sY[tid][71] = 0.f;
  }
  __syncthreads();

  pe_stage<35, 36, 70, 36, 1>(tid, w1, b1, &sIn[0][0], &sX[0][0], wb);
  pe_stage<70, 72, 70, 72, 1>(tid, w2, b2, &sX[0][0], &sY[0][0], wb);
  pe_stage<70, 72, 70, 72, 1>(tid, w3, b3, &sY[0][0], &sX[0][0], wb);

  if (tid < 16) {
    float m = 0.f;
    for (int d = 0; d < 70; ++d) m += sX[tid][d];
    m *= (1.f / 70.f);
    float v = 0.f;
    for (int d = 0; d < 70; ++d) { const float t = sX[tid][d] - m; v += t * t; }
    const float inv = rsqrtf(v * (1.f / 70.f) + 1e-5f);
    for (int d = 0; d < 70; ++d) sX[tid][d] = (sX[tid][d] - m) * inv * lng[d] + lnb[d];
  }
  __syncthreads();

  // final stage: C=128, direct global write with PE row mapping
  {
    for (int i = tid; i < 70 * 128; i += 128) wb[i >> 7][i & 127] = w4[i];
#pragma unroll
    for (int k = 70; k < 72; ++k) wb[k][tid] = 0.f;
    __syncthreads();
    float acc[16];
#pragma unroll
    for (int r = 0; r < 16; ++r) acc[r] = b4[tid];
#pragma unroll 1
    for (int k4 = 0; k4 < 72; k4 += 4) {
      const float w0 = wb[k4 + 0][tid];
      const float w1v = wb[k4 + 1][tid];
      const float w2v = wb[k4 + 2][tid];
      const float w3v = wb[k4 + 3][tid];
#pragma unroll
      for (int r = 0; r < 16; ++r) {
        const float4 av = *(const float4*)&sX[r][k4];
        acc[r] = fmaf(av.x, w0, acc[r]);
        acc[r] = fmaf(av.y, w1v, acc[r]);
        acc[r] = fmaf(av.z, w2v, acc[r]);
        acc[r] = fmaf(av.w, w3v, acc[r]);
      }
    }
#pragma unroll
    for (int r = 0; r < 16; ++r) {
      const int gr = r0 + r;
      x[(size_t)(gr + gr / 1024 + 1) * DIMC + tid] = acc[r];
    }
  }
}

// ---------------------------------------------------------------------------
// bf16 MFMA GEMM, 64x64 tile (mlp1 only now)
// ---------------------------------------------------------------------------
template<int ACT, int OBF, int RES>
__global__ __launch_bounds__(256) void mgemm_k(
    const unsigned short* __restrict__ Xb, const unsigned short* __restrict__ Wt,
    const float* __restrict__ bias, const float* __restrict__ res,
    void* __restrict__ outp, int rows, int K, int N)
{
  __shared__ unsigned short sX[64][72];
  __shared__ unsigned short sW[64][72];
  const int tid = threadIdx.x;
  const int w = tid >> 6, lane = tid & 63;
  const int col = lane & 15, quad = lane >> 4;
  const int r0 = blockIdx.x * 64, n0 = blockIdx.y * 64;
  const int lr = tid >> 2, lc = tid & 3;
  const int xrow = min(r0 + lr, rows - 1);
  const unsigned short* xsrc = Xb + (size_t)xrow * K + lc * 8;
  const unsigned short* wsrc = Wt + (size_t)(n0 + lr) * K + lc * 8;

  f32x4 acc[4];
#pragma unroll
  for (int t = 0; t < 4; ++t) acc[t] = (f32x4){0.f, 0.f, 0.f, 0.f};

  for (int k0 = 0; k0 < K; k0 += 64) {
    __syncthreads();
    *(uint4*)&sX[lr][lc * 8]      = *(const uint4*)(xsrc + k0);
    *(uint4*)&sX[lr][lc * 8 + 32] = *(const uint4*)(xsrc + k0 + 32);
    *(uint4*)&sW[lr][lc * 8]      = *(const uint4*)(wsrc + k0);
    *(uint4*)&sW[lr][lc * 8 + 32] = *(const uint4*)(wsrc + k0 + 32);
    __syncthreads();
    const bf16x8 aX0 = *(const bf16x8*)&sX[w * 16 + col][quad * 8];
    const bf16x8 aX1 = *(const bf16x8*)&sX[w * 16 + col][32 + quad * 8];
#pragma unroll
    for (int t = 0; t < 4; ++t) {
      const bf16x8 bW0 = *(const bf16x8*)&sW[t * 16 + col][quad * 8];
      const bf16x8 bW1 = *(const bf16x8*)&sW[t * 16 + col][32 + quad * 8];
      acc[t] = __builtin_amdgcn_mfma_f32_16x16x32_bf16(aX0, bW0, acc[t], 0, 0, 0);
      acc[t] = __builtin_amdgcn_mfma_f32_16x16x32_bf16(aX1, bW1, acc[t], 0, 0, 0);
    }
  }
  const int gr_base = r0 + w * 16 + quad * 4;
#pragma unroll
  for (int t = 0; t < 4; ++t) {
    const int n = n0 + t * 16 + col;
    const float bv = bias ? bias[n] : 0.f;
#pragma unroll
    for (int r = 0; r < 4; ++r) {
      const int gr = gr_base + r;
      if (gr < rows) {
        float v = acc[t][r] + bv;
        if (ACT) v = gelu_f(v);
        if (RES) v += res[(size_t)gr * N + n];
        if (OBF) ((unsigned short*)outp)[(size_t)gr * N + n] = f2bf(v);
        else     ((float*)outp)[(size_t)gr * N + n] = v;
      }
    }
  }
}

// ---------------------------------------------------------------------------
// R21: bf16 MFMA GEMM with fused LN, 32x128 tile, grid 257 (~1 block/CU).
// R20's 64x128 tile at grid 129 left half the CUs idle — the LN-fusion win
// was eaten by occupancy. Block = 4 waves; wave (rg=w>>1, ch=w&1) owns a
// 16-row x 64-col quadrant (4 MFMA col-tiles). LN row-reduce spans the two
// ch-halves -> partial sum+sumsq per (ch,row) combined through LDS
// (var = E[x^2]-m^2, one barrier); gamma partials get a second barrier.
// ---------------------------------------------------------------------------
template<int DOLN, int GAMMA, int WRITEX>
__global__ __launch_bounds__(256) void mgemm_ln_k(
    const unsigned short* __restrict__ Xb, const unsigned short* __restrict__ Wt,
    const float* __restrict__ bias, const float* __restrict__ res,
    const float* __restrict__ lng, const float* __restrict__ lnb,
    const float* __restrict__ gw, const float* __restrict__ gb,
    float* __restrict__ xout, float* __restrict__ h,
    unsigned short* __restrict__ hb, float* __restrict__ gamout,
    int rows, int K)
{
  __shared__ unsigned short sX[32][72];
  __shared__ unsigned short sW[128][72];
  __shared__ float redS[2][32];
  __shared__ float redQ[2][32];
  __shared__ float redA0[2][32];
  __shared__ float redA1[2][32];
  const int tid = threadIdx.x;
  const int w = tid >> 6, lane = tid & 63;
  const int col = lane & 15, quad = lane >> 4;
  const int rg = w >> 1, ch = w & 1;     // row-group / col-half
  const int r0 = blockIdx.x * 32;

  f32x4 acc[4];
#pragma unroll
  for (int t = 0; t < 4; ++t) acc[t] = (f32x4){0.f, 0.f, 0.f, 0.f};

  for (int k0 = 0; k0 < K; k0 += 64) {
    __syncthreads();
    {
      const int row = tid >> 3, c = tid & 7;       // 32 rows x 64k = 1 pass
      const int xrow = min(r0 + row, rows - 1);
      *(uint4*)&sX[row][c * 8] = *(const uint4*)(Xb + (size_t)xrow * K + k0 + c * 8);
    }
#pragma unroll
    for (int l = 0; l < 4; ++l) {
      const int idx = l * 256 + tid;
      const int row = idx >> 3, c = idx & 7;
      *(uint4*)&sW[row][c * 8] = *(const uint4*)(Wt + (size_t)row * K + k0 + c * 8);
    }
    __syncthreads();
    const bf16x8 aX0 = *(const bf16x8*)&sX[rg * 16 + col][quad * 8];
    const bf16x8 aX1 = *(const bf16x8*)&sX[rg * 16 + col][32 + quad * 8];
#pragma unroll
    for (int t = 0; t < 4; ++t) {
      const bf16x8 bW0 = *(const bf16x8*)&sW[ch * 64 + t * 16 + col][quad * 8];
      const bf16x8 bW1 = *(const bf16x8*)&sW[ch * 64 + t * 16 + col][32 + quad * 8];
      acc[t] = __builtin_amdgcn_mfma_f32_16x16x32_bf16(aX0, bW0, acc[t], 0, 0, 0);
      acc[t] = __builtin_amdgcn_mfma_f32_16x16x32_bf16(aX1, bW1, acc[t], 0, 0, 0);
    }
  }

  // ---- epilogue ----
  const int gr_base = r0 + rg * 16 + quad * 4;
  float val[4][4];
#pragma unroll
  for (int r = 0; r < 4; ++r) {
    const int grc = min(gr_base + r, rows - 1);
#pragma unroll
    for (int t = 0; t < 4; ++t) {
      const int n = ch * 64 + t * 16 + col;
      val[t][r] = acc[t][r] + bias[n] + res[(size_t)grc * DIMC + n];
    }
  }
  if (WRITEX) {
#pragma unroll
    for (int r = 0; r < 4; ++r) {
      const int gr = gr_base + r;
      if (gr < rows) {
#pragma unroll
        for (int t = 0; t < 4; ++t)
          xout[(size_t)gr * DIMC + ch * 64 + t * 16 + col] = val[t][r];
      }
    }
  }
  if (DOLN) {
    // partial sum + sumsq per (ch, row)
#pragma unroll
    for (int r = 0; r < 4; ++r) {
      float s = 0.f, q = 0.f;
#pragma unroll
      for (int t = 0; t < 4; ++t) { s += val[t][r]; q = fmaf(val[t][r], val[t][r], q); }
      s += __shfl_xor(s, 1); s += __shfl_xor(s, 2);
      s += __shfl_xor(s, 4); s += __shfl_xor(s, 8);
      q += __shfl_xor(q, 1); q += __shfl_xor(q, 2);
      q += __shfl_xor(q, 4); q += __shfl_xor(q, 8);
      if (col == 0) {
        const int rl = rg * 16 + quad * 4 + r;
        redS[ch][rl] = s;
        redQ[ch][rl] = q;
      }
    }
    __syncthreads();
    float lg[4], lb[4], gwa[4], gwb[4];
#pragma unroll
    for (int t = 0; t < 4; ++t) {
      const int n = ch * 64 + t * 16 + col;
      lg[t] = lng[n];
      lb[t] = lnb[n];
      if (GAMMA) { gwa[t] = gw[2 * n]; gwb[t] = gw[2 * n + 1]; }
    }
#pragma unroll
    for (int r = 0; r < 4; ++r) {
      const int rl = rg * 16 + quad * 4 + r;
      const int gr = gr_base + r;
      const float S = redS[0][rl] + redS[1][rl];
      const float Q = redQ[0][rl] + redQ[1][rl];
      const float mean = S * (1.f / 128.f);
      const float var = Q * (1.f / 128.f) - mean * mean;
      const float inv = rsqrtf(var + 1e-5f);
      float a0 = 0.f, a1 = 0.f;
#pragma unroll
      for (int t = 0; t < 4; ++t) {
        const float o = (val[t][r] - mean) * inv * lg[t] + lb[t];
        if (gr < rows) {
          const int n = ch * 64 + t * 16 + col;
          h[(size_t)gr * DIMC + n] = o;
          hb[(size_t)gr * DIMC + n] = f2bf(o);
        }
        if (GAMMA) { a0 = fmaf(o, gwa[t], a0); a1 = fmaf(o, gwb[t], a1); }
      }
      if (GAMMA) {
        a0 += __shfl_xor(a0, 1); a0 += __shfl_xor(a0, 2);
        a0 += __shfl_xor(a0, 4); a0 += __shfl_xor(a0, 8);
        a1 += __shfl_xor(a1, 1); a1 += __shfl_xor(a1, 2);
        a1 += __shfl_xor(a1, 4); a1 += __shfl_xor(a1, 8);
        if (col == 0) { redA0[ch][rl] = a0; redA1[ch][rl] = a1; }
      }
    }
    if (GAMMA) {
      __syncthreads();
#pragma unroll
      for (int r = 0; r < 4; ++r) {
        const int rl = rg * 16 + quad * 4 + r;
        const int gr = gr_base + r;
        if (ch == 0 && col == 0 && gr < rows) {
          gamout[(size_t)gr * 2 + 0] = expf(redA0[0][rl] + redA0[1][rl] + gb[0]);
          gamout[(size_t)gr * 2 + 1] = expf(redA1[0][rl] + redA1[1][rl] + gb[1]);
        }
      }
    }
  }
}

// ---------------------------------------------------------------------------
// bf16 MFMA GEMM, 128x128 tile (QKV), with fused V-transpose epilogue
// ---------------------------------------------------------------------------
template<int OBF, int VT>
__global__ __launch_bounds__(256) void mgemm128_k(
    const unsigned short* __restrict__ Xb, const unsigned short* __restrict__ Wt,
    const float* __restrict__ bias, void* __restrict__ outp,
    unsigned short* __restrict__ vtp, int rows, int K, int N)
{
  __shared__ unsigned short sX[128][72];
  __shared__ unsigned short sW[128][72];
  const int tid = threadIdx.x;
  const int w = tid >> 6, lane = tid & 63;
  const int col = lane & 15, quad = lane >> 4;
  const int wr = w >> 1, wc = w & 1;
  const int r0 = blockIdx.x * 128, n0 = blockIdx.y * 128;

  f32x4 acc[4][4];
#pragma unroll
  for (int i = 0; i < 4; ++i)
#pragma unroll
    for (int j = 0; j < 4; ++j) acc[i][j] = (f32x4){0.f, 0.f, 0.f, 0.f};

  for (int k0 = 0; k0 < K; k0 += 64) {
    __syncthreads();
#pragma unroll
    for (int l = 0; l < 4; ++l) {
      const int idx = l * 256 + tid;
      const int row = idx >> 3, c = idx & 7;
      const int xrow = min(r0 + row, rows - 1);
      *(uint4*)&sX[row][c * 8] = *(const uint4*)(Xb + (size_t)xrow * K + k0 + c * 8);
      *(uint4*)&sW[row][c * 8] = *(const uint4*)(Wt + (size_t)(n0 + row) * K + k0 + c * 8);
    }
    __syncthreads();
    bf16x8 aX[4][2];
#pragma unroll
    for (int i = 0; i < 4; ++i) {
      aX[i][0] = *(const bf16x8*)&sX[wr * 64 + i * 16 + col][quad * 8];
      aX[i][1] = *(const bf16x8*)&sX[wr * 64 + i * 16 + col][32 + quad * 8];
    }
#pragma unroll
    for (int j = 0; j < 4; ++j) {
      const bf16x8 b0 = *(const bf16x8*)&sW[wc * 64 + j * 16 + col][quad * 8];
      const bf16x8 b1 = *(const bf16x8*)&sW[wc * 64 + j * 16 + col][32 + quad * 8];
#pragma unroll
      for (int i = 0; i < 4; ++i) {
        acc[i][j] = __builtin_amdgcn_mfma_f32_16x16x32_bf16(aX[i][0], b0, acc[i][j], 0, 0, 0);
        acc[i][j] = __builtin_amdgcn_mfma_f32_16x16x32_bf16(aX[i][1], b1, acc[i][j], 0, 0, 0);
      }
    }
  }
  const bool dovt = VT && (n0 >= 2048);
#pragma unroll
  for (int i = 0; i < 4; ++i) {
    const int gr_base = r0 + wr * 64 + i * 16 + quad * 4;
    int bb[4], mm[4];
    if (dovt) {
#pragma unroll
      for (int r = 0; r < 4; ++r) {
        const int gr = gr_base + r;
        bb[r] = gr / 1025;
        mm[r] = gr - bb[r] * 1025;
      }
    }
#pragma unroll
    for (int j = 0; j < 4; ++j) {
      const int n = n0 + wc * 64 + j * 16 + col;
      const float bv = bias ? bias[n] : 0.f;
      const int hh = (n - 2048) >> 7;
      const int d  = (n - 2048) & 127;
#pragma unroll
      for (int r = 0; r < 4; ++r) {
        const int gr = gr_base + r;
        if (gr < rows) {
          const float v = acc[i][j][r] + bv;
          const unsigned short bf = f2bf(v);
          if (OBF) ((unsigned short*)outp)[(size_t)gr * N + n] = bf;
          else     ((float*)outp)[(size_t)gr * N + n] = v;
          if (dovt) vtp[(((size_t)(bb[r] * NHEADS + hh) * DIMC + d) * ACS) + mm[r]] = bf;
        }
      }
    }
  }
}

// ---------------------------------------------------------------------------
// Wave-per-row LayerNorm; optional bf16 shadow out; optional fused gamma
// (only used once now: initial ln1 after the PE encoder)
// ---------------------------------------------------------------------------
__global__ __launch_bounds__(256) void ln_rows_k(
    const float* __restrict__ in, float* __restrict__ out,
    unsigned short* __restrict__ outb,
    const float* __restrict__ g, const float* __restrict__ b,
    const float* __restrict__ gw, const float* __restrict__ gb,
    float* __restrict__ gamout, int rows, int D)
{
  const int wv = (blockIdx.x * blockDim.x + threadIdx.x) >> 6;
  const int lane = threadIdx.x & 63;
  if (wv >= rows) return;
  const float* r = in + (size_t)wv * D;
  float s = 0.f;
  for (int d = lane; d < D; d += 64) s += r[d];
  for (int off = 32; off; off >>= 1) s += __shfl_down(s, off);
  const float mean = __shfl(s, 0) / (float)D;
  float v = 0.f;
  for (int d = lane; d < D; d += 64) { float t = r[d] - mean; v += t * t; }
  for (int off = 32; off; off >>= 1) v += __shfl_down(v, off);
  const float inv = rsqrtf(__shfl(v, 0) / (float)D + 1e-5f);
  float* orow = out + (size_t)wv * D;
  float a0 = 0.f, a1 = 0.f;
  for (int d = lane; d < D; d += 64) {
    const float o = (r[d] - mean) * inv * g[d] + b[d];
    orow[d] = o;
    if (outb) outb[(size_t)wv * D + d] = f2bf(o);
    if (gw) { a0 = fmaf(o, gw[2 * d], a0); a1 = fmaf(o, gw[2 * d + 1], a1); }
  }
  if (gw) {
    for (int off = 32; off; off >>= 1) { a0 += __shfl_down(a0, off); a1 += __shfl_down(a1, off); }
    if (lane == 0) {
      gamout[(size_t)wv * 2 + 0] = expf(a0 + gb[0]);
      gamout[(size_t)wv * 2 + 1] = expf(a1 + gb[1]);
    }
  }
}

// ---------------------------------------------------------------------------
// prep: bit-packed adj_cls
// ---------------------------------------------------------------------------
__global__ __launch_bounds__(256) void adjp_k(const float* __restrict__ adj,
                                              unsigned long long* __restrict__ adjp)
{
  const int n = blockIdx.x;
  const int b = blockIdx.y;
  const int wv = threadIdx.x >> 6, lane = threadIdx.x & 63;
  for (int w = wv; w < 17; w += 4) {
    const int m = w * 64 + lane;
    float av = 0.f;
    if (n == 0) av = (m == 0) ? 1.f : 0.f;
    else if (m >= 1 && m <= NSEQ) av = adj[((size_t)b * NSEQ + (n - 1)) * NSEQ + (m - 1)];
    const unsigned long long mask = __ballot(av != 0.f);
    if (lane == 0) adjp[((size_t)b * M_ + n) * 17 + w] = mask;
  }
}

// ---------------------------------------------------------------------------
// prep: Wt[n][k] = bf16(W[k][n])
// ---------------------------------------------------------------------------
__global__ void wtrans_k(const float* __restrict__ W, unsigned short* __restrict__ Wt,
                         int K, int N)
{
  __shared__ float t[32][33];
  const int k0 = blockIdx.x * 32, n0 = blockIdx.y * 32;
  const float* Wd = W + (size_t)blockIdx.z * K * N;
  unsigned short* Wtd = Wt + (size_t)blockIdx.z * K * N;
  for (int i = threadIdx.y; i < 32; i += 8)
    t[i][threadIdx.x] = Wd[(size_t)(k0 + i) * N + n0 + threadIdx.x];
  __syncthreads();
  for (int i = threadIdx.y; i < 32; i += 8)
    Wtd[(size_t)(n0 + i) * K + k0 + threadIdx.x] = f2bf(t[threadIdx.x][i]);
}

// ---------------------------------------------------------------------------
// bf16 MFMA flash attention, 8-wave blocks (512 thr).
// Q-tile 256 (32 q-rows/wave, 2 row-groups). Grid (8 heads, 4 q-tiles,
// 8 batch) = 256 blocks = 1/CU. Each bK/bV LDS fragment read feeds TWO
// MFMAs. Single barrier per tile, full-tile-ahead DMA prefetch.
// ---------------------------------------------------------------------------
__global__ __launch_bounds__(512) void attn_mfma_k(
    const unsigned short* __restrict__ qkv, const float* __restrict__ gamma,
    const unsigned long long* __restrict__ adjp, const unsigned short* __restrict__ vt,
    unsigned short* __restrict__ o)
{
  __shared__ unsigned short sK[2][64][128];   // keys, linear rows (DMA dest), 32K
  __shared__ unsigned short sVt[2][128][64];  // transposed V (DMA dest), 32K
  __shared__ unsigned short sP[256][64];      // P; wave w owns rows 32w..32w+31, 32K

  const int hh = blockIdx.x, qt = blockIdx.y, b = blockIdx.z;
  const int tid = threadIdx.x;
  const int w = tid >> 6;                  // 0..7
  const int lane = tid & 63;
  const int col = lane & 15;
  const int quad = lane >> 4;
  const int qbase = qt * 256 + w * 32;     // <= 992; all q-rows valid
  const float scale = 0.088388347648318447f;  // 128^-0.5

  // Q fragments (registers, direct global), 2 row-groups
  bf16x8 aQ[2][4];
#pragma unroll
  for (int rg = 0; rg < 2; ++rg) {
    const int qrow = qbase + rg * 16 + col;
    const unsigned short* qp = qkv + ((size_t)(b * M_ + qrow)) * QKV3 + hh * DIMC + quad * 8;
#pragma unroll
    for (int c = 0; c < 4; ++c) aQ[rg][c] = *(const bf16x8*)(qp + c * 32);
  }
  float g0[2][4], g1[2][4];
  int adjo[2][4];
#pragma unroll
  for (int rg = 0; rg < 2; ++rg)
#pragma unroll
    for (int r = 0; r < 4; ++r) {
      const int nc = qbase + rg * 16 + quad * 4 + r;
      g0[rg][r] = gamma[(size_t)(b * M_ + nc) * 2 + 0] * scale;
      g1[rg][r] = gamma[(size_t)(b * M_ + nc) * 2 + 1];
      adjo[rg][r] = (b * M_ + nc) * 17;
    }

  float l_i[2][4] = {{0.f, 0.f, 0.f, 0.f}, {0.f, 0.f, 0.f, 0.f}};
  f32x4 Oacc[2][8];
#pragma unroll
  for (int rg = 0; rg < 2; ++rg)
#pragma unroll
    for (int t = 0; t < 8; ++t) Oacc[rg][t] = (f32x4){0.f, 0.f, 0.f, 0.f};

  const size_t vtbase = ((size_t)(b * NHEADS + hh)) * DIMC * ACS;

  // DMA staging helpers. LDS dest is wave-uniform base + lane*16B (linear);
  // the bank-conflict swizzle is applied to the GLOBAL source chunk instead.
  auto stageK = [&](int buf, int kt_) {
#pragma unroll
    for (int l = 0; l < 2; ++l) {
      const int m = l * 32 + w * 4 + (lane >> 4);          // row within tile
      const int gm = min(kt_ * 64 + m, 1024);              // clamp (masked later)
      const unsigned short* src = qkv + ((size_t)(b * M_ + gm)) * QKV3 + 1024
                                  + hh * DIMC + (((lane & 15) ^ (m & 7)) * 8);
      g2lds16(src, &sK[buf][l * 32 + w * 4][0]);
    }
  };
  auto stageV = [&](int buf, int kt_) {
#pragma unroll
    for (int l = 0; l < 2; ++l) {
      const int d = l * 64 + w * 8 + (lane >> 3);          // head-dim row
      const unsigned short* src = vt + vtbase + (size_t)d * ACS + kt_ * 64
                                  + (((lane & 7) ^ (d & 7)) * 8);
      g2lds16(src, &sVt[buf][l * 64 + w * 8][0]);
    }
  };

  // prologue: tile-0 K and V DMAs in flight
  stageK(0, 0);
  stageV(0, 0);

  int cur = 0;
  for (int kt = 0; kt < 17; ++kt) {
    const int m0 = kt * 64;
    // Own tile-kt DMAs (issued a full tile ago) must land; one raw barrier
    // publishes all waves' DMA writes. No mid-tile barrier (sP is own-wave).
    asm volatile("s_waitcnt vmcnt(0)" ::: "memory");
    __builtin_amdgcn_s_barrier();
    __builtin_amdgcn_sched_barrier(0);   // keep this tile's LDS reads below

    const bool more = (kt < 16);
    if (more) {
      stageK(cur ^ 1, kt + 1);
      stageV(cur ^ 1, kt + 1);
    }

    // current tile's adj masks — L2-resident, latency hides under QK MFMAs
    unsigned long long mk[2][4];
#pragma unroll
    for (int rg = 0; rg < 2; ++rg)
#pragma unroll
      for (int r = 0; r < 4; ++r) mk[rg][r] = adjp[adjo[rg][r] + kt];

    // S = Q K^T from sK[cur]; each bK read feeds both row-groups
    f32x4 Sacc[2][4];
#pragma unroll
    for (int rg = 0; rg < 2; ++rg)
#pragma unroll
      for (int t = 0; t < 4; ++t) Sacc[rg][t] = (f32x4){0.f, 0.f, 0.f, 0.f};
    __builtin_amdgcn_s_setprio(1);
#pragma unroll
    for (int t = 0; t < 4; ++t) {
#pragma unroll
      for (int c = 0; c < 4; ++c) {
        const bf16x8 bK = *(const bf16x8*)&sK[cur][t * 16 + col][((c * 4 + quad) ^ (col & 7)) * 8];
        Sacc[0][t] = __builtin_amdgcn_mfma_f32_16x16x32_bf16(aQ[0][c], bK, Sacc[0][t], 0, 0, 0);
        Sacc[1][t] = __builtin_amdgcn_mfma_f32_16x16x32_bf16(aQ[1][c], bK, Sacc[1][t], 0, 0, 0);
      }
    }
    __builtin_amdgcn_s_setprio(0);

    // p = exp(g0*S + (bit ? g1 : 0)); write P to LDS (own-wave rows), acc l
#pragma unroll
    for (int t = 0; t < 4; ++t) {
      const int m = m0 + t * 16 + col;
      const bool mv = (m < M_);
      const int chb = t * 2 + (col >> 3);
      const int sh = t * 16 + col;
#pragma unroll
      for (int rg = 0; rg < 2; ++rg)
#pragma unroll
        for (int r = 0; r < 4; ++r) {
          const float bias = ((mk[rg][r] >> sh) & 1ull) ? g1[rg][r] : 0.f;
          const float s = fmaf(g0[rg][r], Sacc[rg][t][r], bias);
          const float pv = mv ? __expf(s) : 0.f;
          l_i[rg][r] += pv;
          const int ql = w * 32 + rg * 16 + quad * 4 + r;
          sP[ql][((chb ^ (ql & 7)) * 8) + (col & 7)] = f2bf(pv);
        }
    }

    // O += P V; each bV read feeds both row-groups. No barrier: sP is
    // same-wave (lgkmcnt-ordered), sVt[cur] published by tile-top barrier.
    __builtin_amdgcn_s_setprio(1);
#pragma unroll
    for (int ch = 0; ch < 2; ++ch) {
      const int pr = w * 32 + col;          // (pr&7)==(pr+16)&7==(col&7)
      const bf16x8 aP0 = *(const bf16x8*)&sP[pr][((ch * 4 + quad) ^ (col & 7)) * 8];
      const bf16x8 aP1 = *(const bf16x8*)&sP[pr + 16][((ch * 4 + quad) ^ (col & 7)) * 8];
#pragma unroll
      for (int t = 0; t < 8; ++t) {
        const bf16x8 bV = *(const bf16x8*)&sVt[cur][t * 16 + col][((ch * 4 + quad) ^ (col & 7)) * 8];
        Oacc[0][t] = __builtin_amdgcn_mfma_f32_16x16x32_bf16(aP0, bV, Oacc[0][t], 0, 0, 0);
        Oacc[1][t] = __builtin_amdgcn_mfma_f32_16x16x32_bf16(aP1, bV, Oacc[1][t], 0, 0, 0);
      }
    }
    __builtin_amdgcn_s_setprio(0);
    cur ^= 1;
  }

  // epilogue: reduce l across the 16-lane col group, O /= l, bf16 out
#pragma unroll
  for (int rg = 0; rg < 2; ++rg)
#pragma unroll
    for (int r = 0; r < 4; ++r) {
      float s = l_i[rg][r];
      s += __shfl_xor(s, 1);
      s += __shfl_xor(s, 2);
      s += __shfl_xor(s, 4);
      s += __shfl_xor(s, 8);
      const int n = qbase + rg * 16 + quad * 4 + r;   // <= 1023, always valid
      const float invl = 1.f / s;
      unsigned short* orow = o + ((size_t)(b * M_ + n)) * (NHEADS * DIMC) + hh * DIMC + col;
#pragma unroll
      for (int t = 0; t < 8; ++t) orow[t * 16] = f2bf(Oacc[rg][t][r] * invl);
    }
}

// ---------------------------------------------------------------------------
// Attention for the single leftover q-row (n = 1024), one block per (b,hh).
// ---------------------------------------------------------------------------
__global__ __launch_bounds__(256) void cls_attn_k(
    const unsigned short* __restrict__ qkv, const float* __restrict__ gamma,
    const unsigned long long* __restrict__ adjp, const unsigned short* __restrict__ vt,
    unsigned short* __restrict__ o)
{
  __shared__ float qf[DIMC];
  __shared__ float pbuf[1056];
  __shared__ float lred[4];
  __shared__ float oshare[DIMC];
  const int hh = blockIdx.x & 7, b = blockIdx.x >> 3;
  const int tid = threadIdx.x;
  const size_t rowbase = (size_t)b * M_ + 1024;

  if (tid < DIMC) qf[tid] = bf2f(qkv[rowbase * QKV3 + hh * DIMC + tid]);
  __syncthreads();
  const float g0 = gamma[rowbase * 2 + 0] * 0.088388347648318447f;
  const float g1 = gamma[rowbase * 2 + 1];

  float lpart = 0.f;
  for (int m = tid; m < M_; m += 256) {
    const unsigned short* kp = qkv + ((size_t)(b * M_ + m)) * QKV3 + 1024 + hh * DIMC;
    float s = 0.f;
#pragma unroll
    for (int d0 = 0; d0 < DIMC; d0 += 8) {
      const bf16x8 kv = *(const bf16x8*)(kp + d0);
#pragma unroll
      for (int j = 0; j < 8; ++j)
        s = fmaf(bf2f((unsigned short)kv[j]), qf[d0 + j], s);
    }
    const unsigned long long mkv = adjp[rowbase * 17 + (m >> 6)];
    const float bias = ((mkv >> (m & 63)) & 1ull) ? g1 : 0.f;
    const float p = __expf(fmaf(g0, s, bias));
    pbuf[m] = p;
    lpart += p;
  }
  for (int off = 32; off; off >>= 1) lpart += __shfl_down(lpart, off);
  if ((tid & 63) == 0) lred[tid >> 6] = lpart;
  __syncthreads();
  const float linv = 1.f / (lred[0] + lred[1] + lred[2] + lred[3]);

  const int d = tid & 127, half = tid >> 7;
  const unsigned short* vrow = vt + ((size_t)(b * NHEADS + hh)) * DIMC * ACS + (size_t)d * ACS;
  float acc = 0.f;
  const int mstart = half * 512;
  const int mend = half ? 1024 : 512;       // half1 tail m=1024 handled below
  for (int m0 = mstart; m0 < mend; m0 += 8) {
    const bf16x8 vv = *(const bf16x8*)(vrow + m0);
#pragma unroll
    for (int j = 0; j < 8; ++j)
      acc = fmaf(bf2f((unsigned short)vv[j]), pbuf[m0 + j], acc);
  }
  if (half) acc = fmaf(bf2f(vrow[1024]), pbuf[1024], acc);
  if (half == 0) oshare[d] = acc;
  __syncthreads();
  if (half == 1) {
    const float val = (oshare[d] + acc) * linv;
    o[rowbase * (NHEADS * DIMC) + hh * DIMC + d] = f2bf(val);
  }
}

// ---------------------------------------------------------------------------
// Head stage: out[8][128] = (optional LN)(in) @ W(128x128) + bias, opt gelu.
// grid 8 blocks x 256 thr; block computes 16 cols x 8 rows, 2-way k-split.
// ---------------------------------------------------------------------------
template<int DOLN, int ACT>
__global__ __launch_bounds__(256) void hstage_k(
    const float* __restrict__ in, int in_stride,
    const float* __restrict__ lng, const float* __restrict__ lnb,
    const float* __restrict__ W, const float* __restrict__ bias,
    float* __restrict__ out)
{
  __shared__ float xn[8][128];
  __shared__ float red[128];
  const int tid = threadIdx.x;
  for (int i = tid; i < 1024; i += 256) {
    const int r = i >> 7, d = i & 127;
    xn[r][d] = in[(size_t)r * in_stride + d];
  }
  __syncthreads();
  if (DOLN) {
    // wave wv: lanes 0-31 handle row 2wv, lanes 32-63 handle row 2wv+1
    const int wv = tid >> 6, lane = tid & 63;
    const int row = wv * 2 + (lane >> 5);
    const int l32 = lane & 31;
    float s = 0.f;
    for (int d = l32; d < 128; d += 32) s += xn[row][d];
    for (int off = 16; off; off >>= 1) s += __shfl_xor(s, off);
    const float mean = s * (1.f / 128.f);
    float v = 0.f;
    for (int d = l32; d < 128; d += 32) { const float t = xn[row][d] - mean; v += t * t; }
    for (int off = 16; off; off >>= 1) v += __shfl_xor(v, off);
    const float inv = rsqrtf(v * (1.f / 128.f) + 1e-5f);
    for (int d = l32; d < 128; d += 32)
      xn[row][d] = (xn[row][d] - mean) * inv * lng[d] + lnb[d];
    __syncthreads();
  }
  const int col = blockIdx.x * 16 + (tid & 15);
  const int row = (tid >> 4) & 7;
  const int ks = tid >> 7;                 // k-split: 0 -> [0,64), 1 -> [64,128)
  float acc = 0.f;
  const int kb = ks * 64;
  for (int k = kb; k < kb + 64; ++k)
    acc = fmaf(xn[row][k], W[k * 128 + col], acc);
  if (ks) red[tid - 128] = acc;
  __syncthreads();
  if (!ks) {
    float v = acc + red[tid] + bias[col];
    if (ACT) v = gelu_f(v);
    out[row * 128 + col] = v;
  }
}

// ---------------------------------------------------------------------------
// Head final: out_p[8][1000] = LN(in) @ pw4 + pb4.
// grid 32 blocks (8 rows x 4 col-chunks of 250) x 256 thr.
// ---------------------------------------------------------------------------
__global__ __launch_bounds__(256) void hfinal_k(
    const float* __restrict__ in,
    const float* __restrict__ plg, const float* __restrict__ plb,
    const float* __restrict__ W, const float* __restrict__ bias,
    float* __restrict__ out_p)
{
  __shared__ float xn[128];
  const int r = blockIdx.x & 7, cc = blockIdx.x >> 3;
  const int tid = threadIdx.x;
  const int lane = tid & 63;
  // each wave redundantly reduces row r (lane covers 2 elems)
  const float a = in[r * 128 + lane];
  const float b = in[r * 128 + 64 + lane];
  float s = a + b;
  for (int off = 32; off; off >>= 1) s += __shfl_xor(s, off);
  const float mean = s * (1.f / 128.f);
  const float t0 = a - mean, t1 = b - mean;
  float v = t0 * t0 + t1 * t1;
  for (int off = 32; off; off >>= 1) v += __shfl_xor(v, off);
  const float inv = rsqrtf(v * (1.f / 128.f) + 1e-5f);
  if (tid < 128) xn[tid] = (in[r * 128 + tid] - mean) * inv * plg[tid] + plb[tid];
  __syncthreads();
  const int col = cc * 250 + tid;
  if (tid < 250) {
    float acc = bias[col];
    for (int k = 0; k < 128; ++k)
      acc = fmaf(xn[k], W[(size_t)k * 1000 + col], acc);
    out_p[r * 1000 + col] = acc;
  }
}

// ---------------------------------------------------------------------------
__global__ void fill_cls_k(const float* __restrict__ cls, float* __restrict__ x)
{
  x[(size_t)blockIdx.x * M_ * DIMC + threadIdx.x] = cls[threadIdx.x];
}

// ---------------------------------------------------------------------------
extern "C" void kernel_launch(void* const* d_in, const int* in_sizes, int n_in,
                              void* d_out, int out_size, void* d_ws, size_t ws_size,
                              hipStream_t stream)
{
  (void)in_sizes; (void)n_in; (void)out_size; (void)ws_size;
  const float* node_feat = (const float*)d_in[0];
  const float* adj       = (const float*)d_in[1];
  const float* lapl      = (const float*)d_in[2];
  const float* cls_token = (const float*)d_in[3];
  const float* pe_w1 = (const float*)d_in[4];
  const float* pe_b1 = (const float*)d_in[5];
  const float* pe_w2 = (const float*)d_in[6];
  const float* pe_b2 = (const float*)d_in[7];
  const float* pe_w3 = (const float*)d_in[8];
  const float* pe_b3 = (const float*)d_in[9];
  const float* pe_lng = (const float*)d_in[10];
  const float* pe_lnb = (const float*)d_in[11];
  const float* pe_w4 = (const float*)d_in[12];
  const float* pe_b4 = (const float*)d_in[13];
  const float* blk_ln1_g = (const float*)d_in[14];
  const float* blk_ln1_b = (const float*)d_in[15];
  const float* blk_qkv_w = (const float*)d_in[16];
  const float* blk_proj_w = (const float*)d_in[17];
  const float* blk_proj_b = (const float*)d_in[18];
  const float* blk_gamma_w = (const float*)d_in[19];
  const float* blk_gamma_b = (const float*)d_in[20];
  const float* blk_ln2_g = (const float*)d_in[21];
  const float* blk_ln2_b = (const float*)d_in[22];
  const float* blk_mlp_w1 = (const float*)d_in[23];
  const float* blk_mlp_b1 = (const float*)d_in[24];
  const float* blk_mlp_w2 = (const float*)d_in[25];
  const float* blk_mlp_b2 = (const float*)d_in[26];
  const float* head_lng = (const float*)d_in[27];
  const float* head_lnb = (const float*)d_in[28];
  const float* head_w = (const float*)d_in[29];
  const float* head_b = (const float*)d_in[30];
  const float* proj_w1 = (const float*)d_in[31];
  const float* proj_b1 = (const float*)d_in[32];
  const float* proj_w2 = (const float*)d_in[33];
  const float* proj_b2 = (const float*)d_in[34];
  const float* proj_w3 = (const float*)d_in[35];
  const float* proj_b3 = (const float*)d_in[36];
  const float* proj_lng = (const float*)d_in[37];
  const float* proj_lnb = (const float*)d_in[38];
  const float* proj_w4 = (const float*)d_in[39];
  const float* proj_b4 = (const float*)d_in[40];

  // ---- workspace layout ----
  float* ws   = (float*)d_ws;
  float* x    = ws;                        // 1,049,600 f
  float* h    = x + 1049600;               // 1,049,600 f
  float* gam  = h + 1049600;               // 16,400 f
  float* obuf = gam + 16400;               // 5,248,000 f region
  unsigned short* obufb = (unsigned short*)obuf;             // 8200*1024 bf16
  unsigned short* hidb  = (unsigned short*)(obuf + 4198400); // 8200*256 bf16
  float* sm  = obuf + 5248000;             // 8,192 f (head scratch p1/p2)
  unsigned short* hb   = (unsigned short*)(sm + 8192);       // 8200*128 bf16
  unsigned short* qkv  = hb + 1049600;     // 25,190,400 us
  unsigned long long* adjp = (unsigned long long*)(qkv + 25190400);  // 139,400 u64
  unsigned short* vt   = (unsigned short*)(adjp + 139400 + 88);      // 8,912,896 us
  unsigned short* qkvWt = vt + 8912896;    // 5*393216
  unsigned short* projWt = qkvWt + 5 * 393216;
  unsigned short* mlp1Wt = projWt + 5 * 131072;
  unsigned short* mlp2Wt = mlp1Wt + 5 * 32768;

  float* out_c = (float*)d_out;            // (8,128)
  float* out_p = out_c + NB * DIMC;        // (8,1000)
  float* p1 = sm;                          // 1024 f
  float* p2 = sm + 1024;                   // 1024 f

  // ---- prep ----
  adjp_k<<<dim3(M_, NB), 256, 0, stream>>>(adj, adjp);
  wtrans_k<<<dim3(4, 96, 5), dim3(32, 8), 0, stream>>>(blk_qkv_w, qkvWt, 128, 3072);
  wtrans_k<<<dim3(32, 4, 5), dim3(32, 8), 0, stream>>>(blk_proj_w, projWt, 1024, 128);
  wtrans_k<<<dim3(4, 8, 5), dim3(32, 8), 0, stream>>>(blk_mlp_w1, mlp1Wt, 128, 256);
  wtrans_k<<<dim3(8, 4, 5), dim3(32, 8), 0, stream>>>(blk_mlp_w2, mlp2Wt, 256, 128);

  // ---- PE encoder ----
  pe_fused_k<<<512, 128, 0, stream>>>(node_feat, lapl, pe_w1, pe_b1, pe_w2, pe_b2,
                                      pe_w3, pe_b3, pe_lng, pe_lnb, pe_w4, pe_b4, x);
  fill_cls_k<<<NB, DIMC, 0, stream>>>(cls_token, x);

  // ---- initial LN1 (layer 0) ----
  const int lnGrid = (ROWS * 64 + 255) / 256;  // 2050
  ln_rows_k<<<lnGrid, 256, 0, stream>>>(x, h, hb, blk_ln1_g, blk_ln1_b,
                                        blk_gamma_w, blk_gamma_b, gam, ROWS, DIMC);

  // ---- transformer layers (LN fused into proj / mlp2 epilogues) ----
  const int fGrid = (ROWS + 31) / 32;  // 257
  for (int i = 0; i < 5; ++i) {
    const float* pb   = blk_proj_b + i * DIMC;
    const float* ln2g = blk_ln2_g + i * DIMC;
    const float* ln2b = blk_ln2_b + i * DIMC;
    const float* mb1  = blk_mlp_b1 + i * 256;
    const float* mb2  = blk_mlp_b2 + i * DIMC;
    const unsigned short* qw = qkvWt + (size_t)i * 393216;
    const unsigned short* pw = projWt + (size_t)i * 131072;
    const unsigned short* m1w = mlp1Wt + (size_t)i * 32768;
    const unsigned short* m2w = mlp2Wt + (size_t)i * 32768;

    mgemm128_k<1, 1><<<dim3(65, 24), 256, 0, stream>>>(hb, qw, nullptr, qkv, vt, ROWS, 128, 3072);
    attn_mfma_k<<<dim3(NHEADS, 4, NB), 512, 0, stream>>>(qkv, gam, adjp, vt, obufb);
    cls_attn_k<<<64, 256, 0, stream>>>(qkv, gam, adjp, vt, obufb);

    // proj + LN2 fused: h(in) is ln1-out residual; h/hb(out) = LN2 result
    mgemm_ln_k<1, 0, 0><<<fGrid, 256, 0, stream>>>(
        obufb, pw, pb, h, ln2g, ln2b, nullptr, nullptr,
        nullptr, h, hb, nullptr, ROWS, 1024);

    mgemm_k<1, 1, 0><<<dim3(129, 4), 256, 0, stream>>>(hb, m1w, mb1, nullptr, hidb, ROWS, 128, 256);

    if (i < 4) {
      // mlp2 + next layer's LN1 + gamma fused
      const float* nln1g = blk_ln1_g + (i + 1) * DIMC;
      const float* nln1b = blk_ln1_b + (i + 1) * DIMC;
      const float* ngw   = blk_gamma_w + (size_t)(i + 1) * DIMC * 2;
      const float* ngb   = blk_gamma_b + (i + 1) * 2;
      mgemm_ln_k<1, 1, 0><<<fGrid, 256, 0, stream>>>(
          hidb, m2w, mb2, h, nln1g, nln1b, ngw, ngb,
          nullptr, h, hb, gam, ROWS, 256);
    } else {
      // last layer: raw x for the head, no LN
      mgemm_ln_k<0, 0, 1><<<fGrid, 256, 0, stream>>>(
          hidb, m2w, mb2, h, nullptr, nullptr, nullptr, nullptr,
          x, nullptr, nullptr, nullptr, ROWS, 256);
    }
  }

  // ---- head: 5 parallel stage kernels ----
  hstage_k<1, 0><<<8, 256, 0, stream>>>(x, M_ * DIMC, head_lng, head_lnb,
                                        head_w, head_b, out_c);
  hstage_k<0, 1><<<8, 256, 0, stream>>>(out_c, 128, nullptr, nullptr,
                                        proj_w1, proj_b1, p1);
  hstage_k<0, 1><<<8, 256, 0, stream>>>(p1, 128, nullptr, nullptr,
                                        proj_w2, proj_b2, p2);
  hstage_k<0, 1><<<8, 256, 0, stream>>>(p2, 128, nullptr, nullptr,
                                        proj_w3, proj_b3, p1);
  hfinal_k<<<32, 256, 0, stream>>>(p1, proj_lng, proj_lnb, proj_w4, proj_b4, out_p);
}